// Round 1
// baseline (21381.088 us; speedup 1.0000x reference)
//
#include <hip/hip_runtime.h>

// LSTM B=32, T=2048, D=256, H=256. relu(x) -> single-layer LSTM (i,f,g,o).
// Persistent kernel: 16 blocks = 2 batch-groups (16 batches) x 8 parts.
// Part p holds W_ih/W_hh rows for hidden units [32p,32p+32) x 4 gates (128 rows)
// as bf16 MFMA B-fragments in registers. Per step: mfma x-part + h-part,
// gates via LDS, elementwise update, h exchanged through global ws with
// device-scope release/acquire flags (parity double-buffered).

#define T_STEPS 2048
#define DDIM 256
#define HDIM 256
#define GROUPS 2
#define PARTS 8
#define NBLOCKS (GROUPS * PARTS)
#define NTHREADS 512

typedef __attribute__((ext_vector_type(8))) short short8;
typedef __attribute__((ext_vector_type(4))) float float4_;

__device__ inline short f2bf(float f) {
    unsigned u = __float_as_uint(f);
    unsigned r = (u + 0x7fffu + ((u >> 16) & 1u)) >> 16;
    return (short)r;
}

__global__ __launch_bounds__(NTHREADS, 2)
void lstm_persistent(const float* __restrict__ x,
                     const float* __restrict__ Wih,
                     const float* __restrict__ Whh,
                     const float* __restrict__ bih,
                     const float* __restrict__ bhh,
                     float* __restrict__ out,
                     unsigned short* __restrict__ hbuf,  // [2 groups][2 parity][16 b][256 u] bf16
                     int* __restrict__ flags)            // [16] at 64B stride
{
    const int tid  = threadIdx.x;
    const int blk  = blockIdx.x;
    const int g    = blk >> 3;   // batch group
    const int p    = blk & 7;    // part (hidden-unit slice)
    const int w    = tid >> 6;   // wave 0..7, one 16x16 N-tile each
    const int lane = tid & 63;
    const int c16  = lane & 15;
    const int quad = lane >> 4;

    __shared__ float gatesLds[128 * 17];
    __shared__ float biasLds[128];

    // ---- bias preload (b_ih + b_hh for this block's 128 gate rows) ----
    if (tid < 128) {
        int r = tid;                                  // local row: gate = r>>5, u = r&31
        int n = ((r >> 5) << 8) + (p << 5) + (r & 31);
        biasLds[r] = bih[n] + bhh[n];
    }

    // ---- weight fragment preload (registers, bf16) ----
    // B-frag layout: lane holds B[k = quad*8 + j][n = lane&15] = W[row(n)][k]
    const int r_row = (w << 4) + c16;                              // local row 0..127
    const int wrow  = ((r_row >> 5) << 8) + (p << 5) + (r_row & 31); // global W row
    const int k0    = quad << 3;

    short8 wih_f[8], whh_f[8];
#pragma unroll
    for (int kt = 0; kt < 8; ++kt) {
        const float* s1 = Wih + wrow * DDIM + kt * 32 + k0;
        const float* s2 = Whh + wrow * HDIM + kt * 32 + k0;
        short8 v1, v2;
#pragma unroll
        for (int j = 0; j < 8; ++j) { v1[j] = f2bf(s1[j]); v2[j] = f2bf(s2[j]); }
        wih_f[kt] = v1;
        whh_f[kt] = v2;
    }

    // ---- x prefetch base: A-frag lane m = lane&15 = batch-in-group ----
    const float* xlane = x + (size_t)(g * 16 + c16) * (size_t)(T_STEPS * DDIM);
    float4_ xraw[16];
#pragma unroll
    for (int kt = 0; kt < 8; ++kt) {
        const float* sx = xlane + kt * 32 + k0;
        xraw[2 * kt]     = *(const float4_*)(sx);
        xraw[2 * kt + 1] = *(const float4_*)(sx + 4);
    }

    // epilogue mapping: one (batch, unit) pair per thread
    const int b_e = tid & 15;
    const int ul  = tid >> 4;           // 0..31
    float c_state = 0.f;

    const int myflag = blk << 4;

    for (int s = 0; s < T_STEPS; ++s) {
        // convert current x frags (relu + bf16)
        short8 xf[8];
#pragma unroll
        for (int kt = 0; kt < 8; ++kt) {
            short8 v;
#pragma unroll
            for (int j = 0; j < 4; ++j) {
                float a = xraw[2 * kt][j];
                float b = xraw[2 * kt + 1][j];
                v[j]     = f2bf(a > 0.f ? a : 0.f);
                v[j + 4] = f2bf(b > 0.f ? b : 0.f);
            }
            xf[kt] = v;
        }
        // prefetch next step's x (independent of recurrence)
        {
            int sn = (s + 1 < T_STEPS) ? s + 1 : s;
            const float* sx = xlane + (size_t)sn * DDIM + k0;
#pragma unroll
            for (int kt = 0; kt < 8; ++kt) {
                xraw[2 * kt]     = *(const float4_*)(sx + kt * 32);
                xraw[2 * kt + 1] = *(const float4_*)(sx + kt * 32 + 4);
            }
        }

        // wait for all 8 parts of this group to have published h(s)
        if (tid < PARTS) {
            const int* fp = flags + ((g * PARTS + tid) << 4);
            while (__hip_atomic_load(fp, __ATOMIC_ACQUIRE, __HIP_MEMORY_SCOPE_AGENT) < s) { }
        }
        __syncthreads();

        // load h(s) A-fragments: lane m = batch, k = unit
        const unsigned short* hsrc =
            hbuf + ((((g * 2 + (s & 1)) * 16) + c16) << 8) + k0;
        short8 hf[8];
#pragma unroll
        for (int kt = 0; kt < 8; ++kt)
            hf[kt] = *(const short8*)(hsrc + kt * 32);

        // gates = relu(x)@Wih^T + h@Whh^T  (two acc chains for ILP)
        float4_ acc0 = {0.f, 0.f, 0.f, 0.f};
        float4_ acc1 = {0.f, 0.f, 0.f, 0.f};
#pragma unroll
        for (int kt = 0; kt < 8; kt += 2) {
            acc0 = __builtin_amdgcn_mfma_f32_16x16x32_bf16(xf[kt],     wih_f[kt],     acc0, 0, 0, 0);
            acc1 = __builtin_amdgcn_mfma_f32_16x16x32_bf16(xf[kt + 1], wih_f[kt + 1], acc1, 0, 0, 0);
        }
#pragma unroll
        for (int kt = 0; kt < 8; kt += 2) {
            acc0 = __builtin_amdgcn_mfma_f32_16x16x32_bf16(hf[kt],     whh_f[kt],     acc0, 0, 0, 0);
            acc1 = __builtin_amdgcn_mfma_f32_16x16x32_bf16(hf[kt + 1], whh_f[kt + 1], acc1, 0, 0, 0);
        }

        // D layout: col = lane&15 = local row r_row, row = quad*4+j = batch
#pragma unroll
        for (int j = 0; j < 4; ++j)
            gatesLds[r_row * 17 + (quad << 2) + j] = acc0[j] + acc1[j];
        __syncthreads();

        // elementwise LSTM cell update (one (b,u) pair per thread)
        {
            float gi = gatesLds[(ul)      * 17 + b_e] + biasLds[ul];
            float gf = gatesLds[(32 + ul) * 17 + b_e] + biasLds[32 + ul];
            float gg = gatesLds[(64 + ul) * 17 + b_e] + biasLds[64 + ul];
            float go = gatesLds[(96 + ul) * 17 + b_e] + biasLds[96 + ul];
            float i_ = 1.f / (1.f + __expf(-gi));
            float f_ = 1.f / (1.f + __expf(-gf));
            float g_ = tanhf(gg);
            float o_ = 1.f / (1.f + __expf(-go));
            c_state  = f_ * c_state + i_ * g_;
            float h_ = o_ * tanhf(c_state);

            hbuf[((((g * 2 + ((s + 1) & 1)) * 16) + b_e) << 8) + (p << 5) + ul] =
                (unsigned short)f2bf(h_);
            out[((size_t)(g * 16 + b_e) * T_STEPS + (size_t)s) * HDIM + (p << 5) + ul] = h_;
        }

        __threadfence();      // make h stores visible at agent scope
        __syncthreads();      // all threads done before publishing
        if (tid == 0)
            __hip_atomic_store(flags + myflag, s + 1,
                               __ATOMIC_RELEASE, __HIP_MEMORY_SCOPE_AGENT);
    }
}

extern "C" void kernel_launch(void* const* d_in, const int* in_sizes, int n_in,
                              void* d_out, int out_size, void* d_ws, size_t ws_size,
                              hipStream_t stream) {
    (void)in_sizes; (void)n_in; (void)out_size; (void)ws_size;
    const float* x   = (const float*)d_in[0];
    const float* Wih = (const float*)d_in[1];
    const float* Whh = (const float*)d_in[2];
    const float* bih = (const float*)d_in[3];
    const float* bhh = (const float*)d_in[4];
    float* out = (float*)d_out;

    unsigned short* hbuf = (unsigned short*)d_ws;                 // 32768 B
    int* flags           = (int*)((char*)d_ws + 32768);           // 16 x 64 B

    hipMemsetAsync(d_ws, 0, 32768 + NBLOCKS * 64, stream);
    hipLaunchKernelGGL(lstm_persistent, dim3(NBLOCKS), dim3(NTHREADS), 0, stream,
                       x, Wih, Whh, bih, bhh, out, hbuf, flags);
}

// Round 2
// 18120.473 us; speedup vs baseline: 1.1799x; 1.1799x over previous
//
#include <hip/hip_runtime.h>

// LSTM B=32, T=2048, D=256, H=256. relu(x) -> single-layer LSTM (i,f,g,o).
// Persistent kernel: 16 blocks = 2 batch-groups (16 batches) x 8 parts.
// Part p holds W_ih/W_hh rows for hidden units [32p,32p+32) x 4 gates (128 rows)
// as bf16 MFMA B-fragments in registers.
// R2 change: ALL cross-block traffic (hbuf, flags) uses relaxed agent-scope
// atomics (sc1 write-through / read-through to MALL). No __threadfence, no
// acquire/release -> no per-step buffer_wbl2 / buffer_inv L2 flushes (R1's
// 6x FETCH over-read). Ordering: __syncthreads' vmcnt(0) drain + explicit
// s_waitcnt before flag publish. x-MFMAs moved BEFORE the spin-wait.

#define T_STEPS 2048
#define DDIM 256
#define HDIM 256
#define GROUPS 2
#define PARTS 8
#define NBLOCKS (GROUPS * PARTS)
#define NTHREADS 512

typedef __attribute__((ext_vector_type(8))) short short8;
typedef __attribute__((ext_vector_type(4))) float float4_;
typedef __attribute__((ext_vector_type(2))) float float2_;

__device__ inline unsigned short f2bf(float f) {
    unsigned u = __float_as_uint(f);
    return (unsigned short)((u + 0x7fffu + ((u >> 16) & 1u)) >> 16);
}
__device__ inline float sigmoid_f(float x) { return 1.f / (1.f + __expf(-x)); }
// branch-free tanh; correct saturation at +/-inf of exp
__device__ inline float tanh_f(float x) { return 1.f - 2.f / (__expf(2.f * x) + 1.f); }

__global__ __launch_bounds__(NTHREADS, 2)
void lstm_persistent(const float* __restrict__ x,
                     const float* __restrict__ Wih,
                     const float* __restrict__ Whh,
                     const float* __restrict__ bih,
                     const float* __restrict__ bhh,
                     float* __restrict__ out,
                     unsigned int* __restrict__ hbuf,  // [2 grp][2 parity][16 b][128 u32] bf16x2
                     int* __restrict__ flags)          // [16] at 64B stride
{
    const int tid  = threadIdx.x;
    const int blk  = blockIdx.x;
    const int g    = blk >> 3;   // batch group
    const int p    = blk & 7;    // part (hidden-unit slice)
    const int w    = tid >> 6;   // wave 0..7, one 16x16 N-tile each
    const int lane = tid & 63;
    const int c16  = lane & 15;
    const int quad = lane >> 4;

    __shared__ float gatesLds[128 * 17];
    __shared__ float biasLds[128];

    if (tid < 128) {
        int n = ((tid >> 5) << 8) + (p << 5) + (tid & 31);
        biasLds[tid] = bih[n] + bhh[n];
    }

    // ---- weight fragment preload (registers, bf16) ----
    const int r_row = (w << 4) + c16;                                // local row 0..127
    const int wrow  = ((r_row >> 5) << 8) + (p << 5) + (r_row & 31); // global W row
    const int k0    = quad << 3;

    short8 wih_f[8], whh_f[8];
#pragma unroll
    for (int kt = 0; kt < 8; ++kt) {
        const float* s1 = Wih + wrow * DDIM + kt * 32 + k0;
        const float* s2 = Whh + wrow * HDIM + kt * 32 + k0;
        short8 v1, v2;
#pragma unroll
        for (int j = 0; j < 8; ++j) { v1[j] = (short)f2bf(s1[j]); v2[j] = (short)f2bf(s2[j]); }
        wih_f[kt] = v1;
        whh_f[kt] = v2;
    }

    // ---- x prefetch: A-frag lane m = lane&15 = batch-in-group ----
    const float* xlane = x + (size_t)(g * 16 + c16) * (size_t)(T_STEPS * DDIM);
    float4_ xraw[16];
#pragma unroll
    for (int kt = 0; kt < 8; ++kt) {
        const float* sx = xlane + kt * 32 + k0;
        xraw[2 * kt]     = *(const float4_*)(sx);
        xraw[2 * kt + 1] = *(const float4_*)(sx + 4);
    }

    // epilogue mapping: threads 0..255, 2 adjacent units each (u32 h-pack)
    const int b_e = tid & 15;
    const int up  = (tid >> 4) & 15;
    float c0 = 0.f, c1 = 0.f;

    const int myflag = blk << 4;

    for (int s = 0; s < T_STEPS; ++s) {
        // ---- x convert (relu + bf16) + x-MFMAs: independent of h, off critical path
        short8 xf[8];
#pragma unroll
        for (int kt = 0; kt < 8; ++kt) {
            short8 v;
#pragma unroll
            for (int j = 0; j < 4; ++j) {
                float a = xraw[2 * kt][j];
                float b = xraw[2 * kt + 1][j];
                v[j]     = (short)f2bf(a > 0.f ? a : 0.f);
                v[j + 4] = (short)f2bf(b > 0.f ? b : 0.f);
            }
            xf[kt] = v;
        }
        float4_ acc0 = {0.f, 0.f, 0.f, 0.f};
        float4_ acc1 = {0.f, 0.f, 0.f, 0.f};
#pragma unroll
        for (int kt = 0; kt < 8; kt += 2) {
            acc0 = __builtin_amdgcn_mfma_f32_16x16x32_bf16(xf[kt],     wih_f[kt],     acc0, 0, 0, 0);
            acc1 = __builtin_amdgcn_mfma_f32_16x16x32_bf16(xf[kt + 1], wih_f[kt + 1], acc1, 0, 0, 0);
        }
        // prefetch next step's x
        {
            int sn = (s + 1 < T_STEPS) ? s + 1 : s;
            const float* sx = xlane + (size_t)sn * DDIM + k0;
#pragma unroll
            for (int kt = 0; kt < 8; ++kt) {
                xraw[2 * kt]     = *(const float4_*)(sx + kt * 32);
                xraw[2 * kt + 1] = *(const float4_*)(sx + kt * 32 + 4);
            }
        }

        // ---- wait for all 8 parts of this group to have published h(s-1)
        if (tid < PARTS) {
            const int* fp = flags + ((g * PARTS + tid) << 4);
            while (__hip_atomic_load(fp, __ATOMIC_RELAXED, __HIP_MEMORY_SCOPE_AGENT) < s) { }
        }
        __syncthreads();   // also a compiler barrier: h loads can't hoist above

        // ---- h A-frag loads, read-through (sc1) relaxed agent atomics
        const unsigned long long* hq = (const unsigned long long*)
            ((const char*)hbuf + (size_t)(((g * 2 + (s & 1)) * 16 + c16) * 512) + (size_t)(k0 * 2));
        short8 hf[8];
#pragma unroll
        for (int kt = 0; kt < 8; ++kt) {
            unsigned long long q0 = __hip_atomic_load(hq + kt * 8,     __ATOMIC_RELAXED, __HIP_MEMORY_SCOPE_AGENT);
            unsigned long long q1 = __hip_atomic_load(hq + kt * 8 + 1, __ATOMIC_RELAXED, __HIP_MEMORY_SCOPE_AGENT);
            union { unsigned long long q[2]; short8 v; } cvt;
            cvt.q[0] = q0; cvt.q[1] = q1;
            hf[kt] = cvt.v;
        }

#pragma unroll
        for (int kt = 0; kt < 8; kt += 2) {
            acc0 = __builtin_amdgcn_mfma_f32_16x16x32_bf16(hf[kt],     whh_f[kt],     acc0, 0, 0, 0);
            acc1 = __builtin_amdgcn_mfma_f32_16x16x32_bf16(hf[kt + 1], whh_f[kt + 1], acc1, 0, 0, 0);
        }

        // D layout: col = lane&15 = local row r_row, row = quad*4+j = batch
#pragma unroll
        for (int j = 0; j < 4; ++j)
            gatesLds[r_row * 17 + (quad << 2) + j] = acc0[j] + acc1[j];
        __syncthreads();

        // ---- elementwise LSTM cell update: threads 0..255, 2 units each
        if (tid < 256) {
            const int u0 = up << 1, u1 = (up << 1) + 1;
            float gi0 = gatesLds[u0 * 17 + b_e]         + biasLds[u0];
            float gf0 = gatesLds[(32 + u0) * 17 + b_e]  + biasLds[32 + u0];
            float gg0 = gatesLds[(64 + u0) * 17 + b_e]  + biasLds[64 + u0];
            float go0 = gatesLds[(96 + u0) * 17 + b_e]  + biasLds[96 + u0];
            float gi1 = gatesLds[u1 * 17 + b_e]         + biasLds[u1];
            float gf1 = gatesLds[(32 + u1) * 17 + b_e]  + biasLds[32 + u1];
            float gg1 = gatesLds[(64 + u1) * 17 + b_e]  + biasLds[64 + u1];
            float go1 = gatesLds[(96 + u1) * 17 + b_e]  + biasLds[96 + u1];

            c0 = sigmoid_f(gf0) * c0 + sigmoid_f(gi0) * tanh_f(gg0);
            c1 = sigmoid_f(gf1) * c1 + sigmoid_f(gi1) * tanh_f(gg1);
            float h0 = sigmoid_f(go0) * tanh_f(c0);
            float h1 = sigmoid_f(go1) * tanh_f(c1);

            // h publish: write-through (sc1) relaxed agent atomic, bf16x2 packed
            unsigned hv = (unsigned)f2bf(h0) | ((unsigned)f2bf(h1) << 16);
            unsigned int* hd = hbuf + (((g * 2 + ((s + 1) & 1)) * 16 + b_e) << 7) + (p << 4) + up;
            __hip_atomic_store(hd, hv, __ATOMIC_RELAXED, __HIP_MEMORY_SCOPE_AGENT);

            float2_ ov = {h0, h1};
            *(float2_*)(out + ((size_t)(g * 16 + b_e) * T_STEPS + (size_t)s) * HDIM + (p << 5) + u0) = ov;
        }

        __builtin_amdgcn_s_waitcnt(0);  // this wave's h stores ack'd at MALL
        __syncthreads();                // all waves done (barrier drains vmcnt)
        if (tid == 0)
            __hip_atomic_store(flags + myflag, s + 1,
                               __ATOMIC_RELAXED, __HIP_MEMORY_SCOPE_AGENT);
    }
}

extern "C" void kernel_launch(void* const* d_in, const int* in_sizes, int n_in,
                              void* d_out, int out_size, void* d_ws, size_t ws_size,
                              hipStream_t stream) {
    (void)in_sizes; (void)n_in; (void)out_size; (void)ws_size;
    const float* x   = (const float*)d_in[0];
    const float* Wih = (const float*)d_in[1];
    const float* Whh = (const float*)d_in[2];
    const float* bih = (const float*)d_in[3];
    const float* bhh = (const float*)d_in[4];
    float* out = (float*)d_out;

    unsigned int* hbuf = (unsigned int*)d_ws;                  // 32768 B
    int* flags         = (int*)((char*)d_ws + 32768);          // 16 x 64 B

    hipMemsetAsync(d_ws, 0, 32768 + NBLOCKS * 64, stream);
    hipLaunchKernelGGL(lstm_persistent, dim3(NBLOCKS), dim3(NTHREADS), 0, stream,
                       x, Wih, Whh, bih, bhh, out, hbuf, flags);
}